// Round 7
// baseline (142.746 us; speedup 1.0000x reference)
//
#include <hip/hip_runtime.h>

// QuantumRegressionModel: 16-qubit statevector, 3 layers x (16 rotations + CNOT chain),
// PauliZ features + linear head. Batch 64, DIM 65536, fp32.
//
// v8 = v7 with ONE bug fixed: Ũ2(b'=4) used evB (= l0^l2^l4^wv0^pB4), but its parity
// set {4,6,8,10,12,14} has NO bit-2 term -> correct w = (l2^l4^wv0^pB4) ^ kk.
// (All 31 kB gate formulas re-derived from parity sets and verified; the rest matched.)
//
// Structure (v7): two passes.
//  * kA (bits {15..9}): 17 gates {U0 w0..6, Ũ1 b=15..10, Ũ2 b'=15..12} — v5's proven
//    scalar schedule in f2 (re,im) packing. Grid 512, 32 f2/thread.
//  * kB (bits {11..0}): 31 gates {U0 w7..15, Ũ1 b=9..0, Ũ2 b'=11..0}, pack dim bit 11
//    (halves r11), h4 = bits{15..12}, grid 1024, 8 f2/thread, LDS 32KB -> 4 blocks/CU.
//    Ũ2(11) (dir {11,9}) crosses the pack dim: partner = swp(slot^2), w = r11^pA4.
//  * Features: sign_q(j) = parity(j & M(15-q)), M=(0x3333<<b)&0xFFFF; bit-11 term per-half.
// Wire q <-> bit (15-q). State = separate re/im fp32 planes.

typedef float f2 __attribute__((ext_vector_type(2)));

struct G8 { float r00,i00,r01,i01,r10,i10,r11,i11; };

__device__ __forceinline__ f2 mkf2(float a, float b) { f2 r; r.x = a; r.y = b; return r; }
__device__ __forceinline__ f2 swp(f2 v) { f2 r; r.x = v.y; r.y = v.x; return r; }
__device__ __forceinline__ f2 sn(f2 v) { f2 r; r.x = -v.y; r.y = v.x; return r; }
__device__ __forceinline__ f2 shf2(f2 v, int mask) {
  return mkf2(__shfl_xor(v.x, mask), __shfl_xor(v.y, mask));
}

__device__ __forceinline__ G8 loadG(const float* p) {
  G8 g;
  g.r00=p[0]; g.i00=p[1]; g.r01=p[2]; g.i01=p[3];
  g.r10=p[4]; g.i10=p[5]; g.r11=p[6]; g.i11=p[7];
  return g;
}

// ---- kA packing: x = (re, im) in one f2. ----
struct CP { f2 dr, di, br, bi; };
__device__ __forceinline__ CP mkCP(const G8& g, int w) {
  CP c;
  const float a = w ? g.r11 : g.r00, b = w ? g.i11 : g.i00;
  const float p = w ? g.r10 : g.r01, q = w ? g.i10 : g.i01;
  c.dr = mkf2(a,a); c.di = mkf2(b,b); c.br = mkf2(p,p); c.bi = mkf2(q,q);
  return c;
}
__device__ __forceinline__ void supdP(const CP& c, f2& x, f2 p) {
  x = __builtin_elementwise_fma(c.dr, x,
       __builtin_elementwise_fma(c.di, sn(x),
        __builtin_elementwise_fma(c.br, p, c.bi * sn(p))));
}

// ---- kB packing: xr/xi hold (r11=0, r11=1) halves; coeffs may differ per half. ----
struct C2 { f2 dr, di, br, bi; };
__device__ __forceinline__ C2 mkC2(const G8& g, int wlo, int whi) {
  C2 c;
  c.dr = mkf2(wlo ? g.r11 : g.r00, whi ? g.r11 : g.r00);
  c.di = mkf2(wlo ? g.i11 : g.i00, whi ? g.i11 : g.i00);
  c.br = mkf2(wlo ? g.r10 : g.r01, whi ? g.r10 : g.r01);
  c.bi = mkf2(wlo ? g.i10 : g.i01, whi ? g.i10 : g.i01);
  return c;
}
__device__ __forceinline__ void supd2(const C2& c, f2& xr, f2& xi, f2 pr, f2 pi) {
  f2 nr = __builtin_elementwise_fma(c.dr, xr,
           __builtin_elementwise_fma(c.di, -xi,
            __builtin_elementwise_fma(c.br, pr, c.bi * (-pi))));
  f2 ni = __builtin_elementwise_fma(c.dr, xi,
           __builtin_elementwise_fma(c.di, xr,
            __builtin_elementwise_fma(c.br, pi, c.bi * pr)));
  xr = nr; xi = ni;
}

__device__ __forceinline__ void buildU(const float* __restrict__ vp, float* U) {
  const int i = threadIdx.x;
  if (i < 48) {
    const float tx = vp[i*6+0], ty = vp[i*6+1], tz = vp[i*6+2];
    float sx, cx, sy, cy, sz, cz;
    sincosf(0.5f*tx, &sx, &cx);
    sincosf(0.5f*ty, &sy, &cy);
    sincosf(0.5f*tz, &sz, &cz);
    const float m00r = cy*cx,  m00i = sy*sx;
    const float m01r = -sy*cx, m01i = -cy*sx;
    const float m10r = sy*cx,  m10i = -cy*sx;
    const float m11r = cy*cx,  m11i = -sy*sx;
    float* o = U + i*8;
    o[0] = cz*m00r + sz*m00i;  o[1] = cz*m00i - sz*m00r;
    o[2] = cz*m01r + sz*m01i;  o[3] = cz*m01i - sz*m01r;
    o[4] = cz*m10r - sz*m10i;  o[5] = cz*m10i + sz*m10r;
    o[6] = cz*m11r - sz*m11i;  o[7] = cz*m11i + sz*m11r;
  }
}

#define GU(l, w) loadG(Ush + ((l)*16 + (w))*8)

// ---------------- Pass A: bits {15..9}, 17 gates, (re,im)-packed -------------
// j = k<<11 | l5<<10 | l4<<9 | c<<6 | wv<<4 | (l&15). Grid: 64 batch x 8 c.
__global__ void __launch_bounds__(256, 2)
kA(const float* __restrict__ sr, const float* __restrict__ si,
   float* __restrict__ dr, float* __restrict__ di,
   const float* __restrict__ vp, const float* __restrict__ hb, float* __restrict__ out) {
  __shared__ float Ush[384];
  buildU(vp, Ush);
  const int t = threadIdx.x;
  const int l = t & 63, wv = t >> 6;
  const int l5 = (l >> 5) & 1, l4 = (l >> 4) & 1;
  const int b = blockIdx.x >> 3, c = blockIdx.x & 7;
  if (blockIdx.x == 0 && t < 64) out[t] = hb[0];     // head bias init
  __syncthreads();

  const size_t bb = (size_t)b << 16;
  const int tb = (l5 << 10) | (l4 << 9) | (c << 6) | (wv << 4) | (l & 15);
  f2 x[32];
  #pragma unroll
  for (int k = 0; k < 32; ++k) {
    const size_t a = bb + (k << 11) + tb;
    x[k] = mkf2(sr[a], si[a]);
  }

#define RPA(CA, CB, A, B) { f2 tt = x[A]; supdP(CA, x[A], x[B]); supdP(CB, x[B], tt); }

  // U0 wires 0..4 on k-bits 4..0
  #pragma unroll
  for (int g = 0; g < 5; ++g) {
    const int kb = 4 - g;
    const G8 U = GU(0, g);
    const CP c0 = mkCP(U, 0), c1 = mkCP(U, 1);
    #pragma unroll
    for (int p = 0; p < 16; ++p) {
      const int i0 = ((p >> kb) << (kb + 1)) | (p & ((1 << kb) - 1));
      RPA(c0, c1, i0, i0 | (1 << kb));
    }
  }
  // U0 wire5 (bit10 = lane mask 32)
  { const G8 U = GU(0,5); const CP cc = mkCP(U, l5);
    #pragma unroll
    for (int a = 0; a < 32; ++a) supdP(cc, x[a], shf2(x[a], 32)); }
  // U0 wire6 (bit9 = lane mask 16)
  { const G8 U = GU(0,6); const CP cc = mkCP(U, l4);
    #pragma unroll
    for (int a = 0; a < 32; ++a) supdP(cc, x[a], shf2(x[a], 16)); }
  // Ũ1 b=15: ^24, rep k4=0, flip 0
  { const G8 U = GU(1,0); const CP c0 = mkCP(U,0), c1 = mkCP(U,1);
    #pragma unroll
    for (int k = 0; k < 32; ++k) if (!((k>>4)&1)) RPA(c0, c1, k, k^24); }
  // Ũ1 b=14: ^12, rep k3=0, flip k4
  { const G8 U = GU(1,1); const CP c0 = mkCP(U,0), c1 = mkCP(U,1);
    #pragma unroll
    for (int k = 0; k < 32; ++k) if (!((k>>3)&1)) {
      const int f = (k>>4)&1;
      RPA(f?c1:c0, f?c0:c1, k, k^12);
    } }
  // Ũ1 b=13: ^6, rep k2=0, flip k4^k3
  { const G8 U = GU(1,2); const CP c0 = mkCP(U,0), c1 = mkCP(U,1);
    #pragma unroll
    for (int k = 0; k < 32; ++k) if (!((k>>2)&1)) {
      const int f = ((k>>4)^(k>>3))&1;
      RPA(f?c1:c0, f?c0:c1, k, k^6);
    } }
  // Ũ1 b=12: ^3, rep k1=0, flip k4^k3^k2
  { const G8 U = GU(1,3); const CP c0 = mkCP(U,0), c1 = mkCP(U,1);
    #pragma unroll
    for (int k = 0; k < 32; ++k) if (!((k>>1)&1)) {
      const int f = ((k>>4)^(k>>3)^(k>>2))&1;
      RPA(f?c1:c0, f?c0:c1, k, k^3);
    } }
  // Ũ1 b=11: dir k0 x lane32; per-amp w = popc(k)
  { const G8 U = GU(1,4); const CP c0 = mkCP(U,0), c1 = mkCP(U,1);
    #pragma unroll
    for (int m = 0; m < 16; ++m) {
      const int k0 = 2*m, k1 = 2*m+1;
      f2 p0 = shf2(x[k1], 32), p1 = shf2(x[k0], 32);
      const int w0 = __builtin_popcount(k0)&1;
      supdP(w0?c1:c0, x[k0], p0);
      supdP(w0?c0:c1, x[k1], p1);
    } }
  // Ũ1 b=10: dir lane{5,4} mask 48; w = popc(k)^l5
  { const G8 U = GU(1,5); const CP cA = mkCP(U, l5), cB = mkCP(U, l5^1);
    #pragma unroll
    for (int k = 0; k < 32; ++k) {
      f2 p = shf2(x[k], 48);
      supdP((__builtin_popcount(k)&1)?cB:cA, x[k], p);
    } }
  // Ũ2 b'=15: ^20, rep k4=0, flip 0
  { const G8 U = GU(2,0); const CP c0 = mkCP(U,0), c1 = mkCP(U,1);
    #pragma unroll
    for (int k = 0; k < 32; ++k) if (!((k>>4)&1)) RPA(c0, c1, k, k^20); }
  // Ũ2 b'=14: ^10, rep k3=0, flip 0
  { const G8 U = GU(2,1); const CP c0 = mkCP(U,0), c1 = mkCP(U,1);
    #pragma unroll
    for (int k = 0; k < 32; ++k) if (!((k>>3)&1)) RPA(c0, c1, k, k^10); }
  // Ũ2 b'=13: ^5, rep k2=0, flip k4
  { const G8 U = GU(2,2); const CP c0 = mkCP(U,0), c1 = mkCP(U,1);
    #pragma unroll
    for (int k = 0; k < 32; ++k) if (!((k>>2)&1)) {
      const int f = (k>>4)&1;
      RPA(f?c1:c0, f?c0:c1, k, k^5);
    } }
  // Ũ2 b'=12: dir k1 x lane32; rep k1=0; w0 = k3
  { const G8 U = GU(2,3); const CP c0 = mkCP(U,0), c1 = mkCP(U,1);
    #pragma unroll
    for (int k = 0; k < 32; ++k) if (!((k>>1)&1)) {
      f2 p0 = shf2(x[k^2], 32), p1 = shf2(x[k], 32);
      const int f = (k>>3)&1;
      supdP(f?c1:c0, x[k], p0);
      supdP(f?c0:c1, x[k^2], p1);
    } }

  #pragma unroll
  for (int k = 0; k < 32; ++k) {
    const size_t a = bb + (k << 11) + tb;
    dr[a] = x[k].x; di[a] = x[k].y;
  }
#undef RPA
}

// ---------------- Pass B: bits {11..0}, 31 gates, bit11-packed ---------------
// Layout A (stages 1,3): slots s = kk*4+e, kk = bit10, e = bits{1,0}; lanes bits{7..2};
//   waves bits{9,8}; halves r11. Grid: 64 batch x h4 = bits{15..12} -> 1024 blocks.
// Layout B (stage 2, via swizzled LDS retile {9,8}<->{1,0}): slots s3 = bits{10,9,8}.
// LDS: 2048 f2 x 2 planes = 32 KB -> 4 blocks/CU.
__device__ __forceinline__ int SA2(int i) { return i ^ (((i >> 5) & 7) << 1); }

__global__ void __launch_bounds__(256, 4)
kB(const float* __restrict__ sr, const float* __restrict__ si,
   const float* __restrict__ vp, const float* __restrict__ hw, float* __restrict__ out) {
  __shared__ float lds[8192];
  __shared__ float Ush[384];
  __shared__ float red[4];
  buildU(vp, Ush);
  const int t = threadIdx.x;
  const int l = t & 63, wv = t >> 6;
  const int b = blockIdx.x >> 4, h4 = blockIdx.x & 15;
  __syncthreads();

  const int ph4 = __builtin_popcount(h4) & 1;       // parity bits {15..12}
  const int pA4 = ((h4 >> 1) ^ (h4 >> 3)) & 1;      // bit13 ^ bit15
  const int pB4 = (h4 ^ (h4 >> 2)) & 1;             // bit12 ^ bit14
  const size_t base0 = ((size_t)b << 16) | (h4 << 12) | (wv << 8) | (l << 2);

  f2 xr2[8], xi2[8];                                 // s = kk*4 + e; halves = r11
  #pragma unroll
  for (int kk = 0; kk < 2; ++kk) {
    const float4 r0 = *(const float4*)(sr + base0 + (kk << 10));
    const float4 r1 = *(const float4*)(sr + base0 + (kk << 10) + 2048);
    const float4 i0 = *(const float4*)(si + base0 + (kk << 10));
    const float4 i1 = *(const float4*)(si + base0 + (kk << 10) + 2048);
    xr2[kk*4+0] = mkf2(r0.x, r1.x); xr2[kk*4+1] = mkf2(r0.y, r1.y);
    xr2[kk*4+2] = mkf2(r0.z, r1.z); xr2[kk*4+3] = mkf2(r0.w, r1.w);
    xi2[kk*4+0] = mkf2(i0.x, i1.x); xi2[kk*4+1] = mkf2(i0.y, i1.y);
    xi2[kk*4+2] = mkf2(i0.z, i1.z); xi2[kk*4+3] = mkf2(i0.w, i1.w);
  }

#define RP2(CA, CB, A, B) { f2 tr = xr2[A], ti = xi2[A]; \
    supd2(CA, xr2[A], xi2[A], xr2[B], xi2[B]); \
    supd2(CB, xr2[B], xi2[B], tr, ti); }

  // ======== Stage 1 (layout A): U0 bits 7..0 ========
  #pragma unroll
  for (int g = 0; g < 6; ++g) {                      // wires 8..13 = lane masks 32..1
    const int mask = 32 >> g;
    const G8 U = GU(0, 8 + g);
    const int hi = (l >> (5 - g)) & 1;
    const C2 cc = mkC2(U, hi, hi);
    #pragma unroll
    for (int s = 0; s < 8; ++s) {
      f2 pr = shf2(xr2[s], mask), pi = shf2(xi2[s], mask);
      supd2(cc, xr2[s], xi2[s], pr, pi);
    }
  }
  { const G8 U = GU(0,14);                           // wire 14 = bit1 = e1
    const C2 c0 = mkC2(U,0,0), c1 = mkC2(U,1,1);
    #pragma unroll
    for (int kk = 0; kk < 2; ++kk)
      #pragma unroll
      for (int e0 = 0; e0 < 2; ++e0) RP2(c0, c1, kk*4+e0, kk*4+e0+2); }
  { const G8 U = GU(0,15);                           // wire 15 = bit0 = e0
    const C2 c0 = mkC2(U,0,0), c1 = mkC2(U,1,1);
    #pragma unroll
    for (int kk = 0; kk < 2; ++kk) {
      RP2(c0, c1, kk*4+0, kk*4+1);
      RP2(c0, c1, kk*4+2, kk*4+3);
    } }

  // ---- retile A -> B (swap bits {9,8} <-> {1,0}), b64 swizzled ----
  #pragma unroll
  for (int kk = 0; kk < 2; ++kk)
    #pragma unroll
    for (int e = 0; e < 4; ++e) {
      const int fi = ((kk << 10) | (wv << 8) | (l << 2) | e) << 1;
      *(f2*)&lds[SA2(fi)] = xr2[kk*4+e];
      *(f2*)&lds[4096 + SA2(fi)] = xi2[kk*4+e];
    }
  __syncthreads();
  #pragma unroll
  for (int s3 = 0; s3 < 8; ++s3) {
    const int fi = ((s3 << 8) | (l << 2) | wv) << 1;
    xr2[s3] = *(f2*)&lds[SA2(fi)];
    xi2[s3] = *(f2*)&lds[4096 + SA2(fi)];
  }

  // ======== Stage 2 (layout B: s3 bits {10,9,8}) ========
  const int l5=(l>>5)&1, l4=(l>>4)&1, l3=(l>>3)&1, l2=(l>>2)&1, l1=(l>>1)&1, l0=l&1;
  { const G8 U = GU(0,7);                            // U0 wire 7 = bit8 = s3 bit0
    const C2 c0 = mkC2(U,0,0), c1 = mkC2(U,1,1);
    #pragma unroll
    for (int s3 = 0; s3 < 8; s3 += 2) RP2(c0, c1, s3, s3^1); }
  // Ũ1 b=9 (w6): pairs s3^3; rep b9=0; flip = ph4 ^ r11 ^ b10
  { const G8 U = GU(1,6);
    const C2 cA = mkC2(U, ph4, ph4^1), cB = mkC2(U, ph4^1, ph4);
    #pragma unroll
    for (int s3 = 0; s3 < 8; ++s3) if (!((s3>>1)&1)) {
      const int f = (s3>>2)&1;
      RP2(f?cB:cA, f?cA:cB, s3, s3^3);
    } }
  // Ũ1 b=8 (w7): dir s3bit0 x lane32; w = ph4^r11^b10^b9^b8
  { const G8 U = GU(1,7);
    const C2 cA = mkC2(U, ph4, ph4^1), cB = mkC2(U, ph4^1, ph4);
    #pragma unroll
    for (int s3 = 0; s3 < 8; s3 += 2) {
      f2 p0r = shf2(xr2[s3^1],32), p0i = shf2(xi2[s3^1],32);
      f2 p1r = shf2(xr2[s3],32),   p1i = shf2(xi2[s3],32);
      const int f = ((s3>>2)^(s3>>1))&1;
      supd2(f?cB:cA, xr2[s3], xi2[s3], p0r, p0i);
      supd2(f?cA:cB, xr2[s3^1], xi2[s3^1], p1r, p1i);
    } }
  // Ũ1 b=7..3 (w8..12): lane masks 48,24,12,6,3; w = lp ^ ph4 ^ r11 ^ popc(s3)
  #pragma unroll
  for (int g = 0; g < 5; ++g) {
    const int mask = 48 >> g;
    const G8 U = GU(1, 8 + g);
    const int lp = (g==0)? l5 : (g==1)? (l4^l5) : (g==2)? (l3^l4^l5)
                 : (g==3)? (l2^l3^l4^l5) : (l1^l2^l3^l4^l5);
    const C2 cA = mkC2(U, (lp^ph4)&1, (lp^ph4^1)&1);
    const C2 cB = mkC2(U, (lp^ph4^1)&1, (lp^ph4)&1);
    #pragma unroll
    for (int s3 = 0; s3 < 8; ++s3) {
      f2 pr = shf2(xr2[s3], mask), pi = shf2(xi2[s3], mask);
      supd2((__builtin_popcount(s3)&1)?cB:cA, xr2[s3], xi2[s3], pr, pi);
    }
  }
  // Ũ2 b'=11 (w4): dir {11,9} crosses pack: partner = swp(s3^2); w = r11^pA4
  { const G8 U = GU(2,4);
    const C2 cc = mkC2(U, pA4, pA4^1);
    #pragma unroll
    for (int s3 = 0; s3 < 8; ++s3) if (!((s3>>1)&1)) {
      f2 tr = xr2[s3], ti = xi2[s3];
      supd2(cc, xr2[s3], xi2[s3], swp(xr2[s3^2]), swp(xi2[s3^2]));
      supd2(cc, xr2[s3^2], xi2[s3^2], swp(tr), swp(ti));
    } }
  // Ũ2 b'=10 (w5): pairs s3^5; rep b10=0; flip = pB4
  { const G8 U = GU(2,5);
    const C2 cA = mkC2(U, pB4, pB4), cB = mkC2(U, pB4^1, pB4^1);
    #pragma unroll
    for (int s3 = 0; s3 < 4; ++s3) RP2(cA, cB, s3, s3^5); }
  // Ũ2 b'=9 (w6): dir s3bit1 x lane32; w(b9=0) = r11^pA4
  { const G8 U = GU(2,6);
    const C2 cA = mkC2(U, pA4, pA4^1), cB = mkC2(U, pA4^1, pA4);
    #pragma unroll
    for (int s3 = 0; s3 < 8; ++s3) if (!((s3>>1)&1)) {
      f2 p0r = shf2(xr2[s3^2],32), p0i = shf2(xi2[s3^2],32);
      f2 p1r = shf2(xr2[s3],32),   p1i = shf2(xi2[s3],32);
      supd2(cA, xr2[s3], xi2[s3], p0r, p0i);
      supd2(cB, xr2[s3^2], xi2[s3^2], p1r, p1i);
    } }
  // Ũ2 b'=8 (w7): dir s3bit0 x lane16; w(b8=0) = b10^pB4
  { const G8 U = GU(2,7);
    const C2 cA = mkC2(U, pB4, pB4), cB = mkC2(U, pB4^1, pB4^1);
    #pragma unroll
    for (int s3 = 0; s3 < 8; s3 += 2) {
      f2 p0r = shf2(xr2[s3^1],16), p0i = shf2(xi2[s3^1],16);
      f2 p1r = shf2(xr2[s3],16),   p1i = shf2(xi2[s3],16);
      const int f = (s3>>2)&1;
      supd2(f?cB:cA, xr2[s3], xi2[s3], p0r, p0i);
      supd2(f?cA:cB, xr2[s3^1], xi2[s3^1], p1r, p1i);
    } }
  // Ũ2 b'=7,6,5 (w8,9,10): lane masks 40,20,10
  #pragma unroll
  for (int g = 0; g < 3; ++g) {
    const int mask = (g == 0) ? 40 : (g == 1) ? 20 : 10;
    const G8 U = GU(2, 8 + g);
    int mpar, blo, bhi;
    if      (g == 0) { mpar = 2; blo = (l5^pA4)&1;      bhi = blo^1; }  // w = l5^b9^r11^pA4
    else if (g == 1) { mpar = 5; blo = (l4^pB4)&1;      bhi = blo;   }  // w = l4^b8^b10^pB4
    else             { mpar = 2; blo = (l3^l5^pA4)&1;   bhi = blo^1; }  // w = l3^l5^b9^r11^pA4
    const C2 cA = mkC2(U, blo, bhi), cB = mkC2(U, blo^1, bhi^1);
    #pragma unroll
    for (int s3 = 0; s3 < 8; ++s3) {
      f2 pr = shf2(xr2[s3], mask), pi = shf2(xi2[s3], mask);
      supd2((__builtin_popcount(s3 & mpar)&1)?cB:cA, xr2[s3], xi2[s3], pr, pi);
    }
  }

  // ---- retile B -> A ----
  __syncthreads();
  #pragma unroll
  for (int s3 = 0; s3 < 8; ++s3) {
    const int fi = ((s3 << 8) | (l << 2) | wv) << 1;
    *(f2*)&lds[SA2(fi)] = xr2[s3];
    *(f2*)&lds[4096 + SA2(fi)] = xi2[s3];
  }
  __syncthreads();
  #pragma unroll
  for (int kk = 0; kk < 2; ++kk)
    #pragma unroll
    for (int e = 0; e < 4; ++e) {
      const int fi = ((kk << 10) | (wv << 8) | (l << 2) | e) << 1;
      xr2[kk*4+e] = *(f2*)&lds[SA2(fi)];
      xi2[kk*4+e] = *(f2*)&lds[4096 + SA2(fi)];
    }

  // ======== Stage 3 (layout A) ========
  const int wv1 = (wv >> 1) & 1, wv0 = wv & 1;
  const int RPlo  = (__builtin_popcount(l) ^ __builtin_popcount(wv) ^ ph4) & 1;
  const int oddTl = (l1 ^ l3 ^ l5 ^ wv1 ^ pA4) & 1;
  const int evB   = (l0 ^ l2 ^ l4 ^ wv0 ^ pB4) & 1;
  // Ũ1 b=2 (w13): lane-mask1 x e1; w = RPlo ^ r11 ^ kk
  { const G8 U = GU(1,13);
    const C2 cA = mkC2(U, RPlo, RPlo^1), cB = mkC2(U, RPlo^1, RPlo);
    #pragma unroll
    for (int kk = 0; kk < 2; ++kk) {
      const C2& cc = kk ? cB : cA;
      #pragma unroll
      for (int e0 = 0; e0 < 2; ++e0) {
        const int a = kk*4 + e0, a2 = a + 2;
        f2 par = shf2(xr2[a2],1), pai = shf2(xi2[a2],1);
        f2 pbr = shf2(xr2[a],1),  pbi = shf2(xi2[a],1);
        supd2(cc, xr2[a],  xi2[a],  par, pai);
        supd2(cc, xr2[a2], xi2[a2], pbr, pbi);
      }
    } }
  // Ũ1 b=1 (w14): pairs (0,3),(1,2); flip = RPlo ^ r11 ^ kk
  { const G8 U = GU(1,14);
    const C2 cA = mkC2(U, RPlo, RPlo^1), cB = mkC2(U, RPlo^1, RPlo);
    #pragma unroll
    for (int kk = 0; kk < 2; ++kk) {
      RP2(kk?cB:cA, kk?cA:cB, kk*4+0, kk*4+3);
      RP2(kk?cB:cA, kk?cA:cB, kk*4+1, kk*4+2);
    } }
  // Ũ1 b=0 (w15): pairs s^1; flip = RPlo ^ r11 ^ kk ^ e1
  { const G8 U = GU(1,15);
    const C2 cA = mkC2(U, RPlo, RPlo^1), cB = mkC2(U, RPlo^1, RPlo);
    #pragma unroll
    for (int kk = 0; kk < 2; ++kk) {
      RP2(kk?cB:cA, kk?cA:cB, kk*4+0, kk*4+1);
      RP2(kk?cA:cB, kk?cB:cA, kk*4+2, kk*4+3);
    } }
  // Ũ2 b'=4 (w11): lane mask 5; parity set {4,6,8,10,12,14} -> w = (l2^l4^wv0^pB4) ^ kk
  // *** v8 FIX: was evB (spurious l0 term; l0 = bit2 is NOT in this parity set) ***
  { const G8 U = GU(2,11);
    const int b4 = (l2 ^ l4 ^ wv0 ^ pB4) & 1;
    const C2 cA = mkC2(U, b4, b4), cB = mkC2(U, b4^1, b4^1);
    #pragma unroll
    for (int s = 0; s < 8; ++s) {
      f2 pr = shf2(xr2[s], 5), pi = shf2(xi2[s], 5);
      supd2((s>>2)?cB:cA, xr2[s], xi2[s], pr, pi);
    } }
  // Ũ2 b'=3 (w12): lane-mask2 x e1; w = oddTl ^ r11 (no kk)
  { const G8 U = GU(2,12);
    const C2 cc = mkC2(U, oddTl, oddTl^1);
    #pragma unroll
    for (int kk = 0; kk < 2; ++kk)
      #pragma unroll
      for (int e0 = 0; e0 < 2; ++e0) {
        const int a = kk*4 + e0, a2 = a + 2;
        f2 par = shf2(xr2[a2],2), pai = shf2(xi2[a2],2);
        f2 pbr = shf2(xr2[a],2),  pbi = shf2(xi2[a],2);
        supd2(cc, xr2[a],  xi2[a],  par, pai);
        supd2(cc, xr2[a2], xi2[a2], pbr, pbi);
      } }
  // Ũ2 b'=2 (w13): lane-mask1 x e0; w = evB ^ kk
  { const G8 U = GU(2,13);
    const C2 cA = mkC2(U, evB, evB), cB = mkC2(U, evB^1, evB^1);
    #pragma unroll
    for (int kk = 0; kk < 2; ++kk) {
      const C2& cc = kk ? cB : cA;
      #pragma unroll
      for (int e0 = 0; e0 < 4; e0 += 2) {
        const int a = kk*4 + e0, a2 = a + 1;
        f2 par = shf2(xr2[a2],1), pai = shf2(xi2[a2],1);
        f2 pbr = shf2(xr2[a],1),  pbi = shf2(xi2[a],1);
        supd2(cc, xr2[a],  xi2[a],  par, pai);
        supd2(cc, xr2[a2], xi2[a2], pbr, pbi);
      }
    } }
  // Ũ2 b'=1 (w14): pairs s^2; flip = oddTl ^ r11
  { const G8 U = GU(2,14);
    const C2 cA = mkC2(U, oddTl, oddTl^1), cB = mkC2(U, oddTl^1, oddTl);
    #pragma unroll
    for (int kk = 0; kk < 2; ++kk) {
      RP2(cA, cB, kk*4+0, kk*4+2);
      RP2(cA, cB, kk*4+1, kk*4+3);
    } }
  // Ũ2 b'=0 (w15): pairs s^1; flip = evB ^ kk
  { const G8 U = GU(2,15);
    const C2 cA = mkC2(U, evB, evB), cB = mkC2(U, evB^1, evB^1);
    #pragma unroll
    for (int kk = 0; kk < 2; ++kk) {
      RP2(kk?cB:cA, kk?cA:cB, kk*4+0, kk*4+1);
      RP2(kk?cB:cA, kk?cA:cB, kk*4+2, kk*4+3);
    } }

  // ======== Features (P^3 fold, bit11 per-half) + head ========
  #pragma unroll
  for (int s = 0; s < 8; ++s)
    xr2[s] = xr2[s]*xr2[s] + xi2[s]*xi2[s];          // reuse as |amp|^2
  const int jloc = (h4 << 12) | (wv << 8) | (l << 2);
  float hsum = 0.f;
  #pragma unroll
  for (int q = 0; q < 16; ++q) {
    const int M = (0x3333 << (15 - q)) & 0xFFFF;
    f2 acc = mkf2(0.f, 0.f);
    #pragma unroll
    for (int s = 0; s < 8; ++s) {
      const int amp = ((s >> 2) << 10) | (s & 3);
      if (__builtin_popcount(amp & M) & 1) acc -= xr2[s]; else acc += xr2[s];
    }
    float sv = acc.x + (((M >> 11) & 1) ? -acc.y : acc.y);
    if (__builtin_popcount(jloc & M) & 1) sv = -sv;
    hsum += hw[q] * sv;
  }
  #pragma unroll
  for (int o = 32; o >= 1; o >>= 1) hsum += __shfl_xor(hsum, o);
  if ((t & 63) == 0) red[wv] = hsum;
  __syncthreads();
  if (t == 0) atomicAdd(out + b, red[0] + red[1] + red[2] + red[3]);
#undef RP2
}

extern "C" void kernel_launch(void* const* d_in, const int* in_sizes, int n_in,
                              void* d_out, int out_size, void* d_ws, size_t ws_size,
                              hipStream_t stream) {
  const float* in_r = (const float*)d_in[0];  // (64, 65536) fp32
  const float* in_i = (const float*)d_in[1];
  const float* vp = (const float*)d_in[2];    // (3,16,6)
  const float* hw = (const float*)d_in[3];    // (1,16)
  const float* hb = (const float*)d_in[4];    // (1,)
  float* out = (float*)d_out;                 // (64,) fp32

  float* ws_r = (float*)d_ws;                 // 4,194,304 floats
  float* ws_i = ws_r + 4194304ull;

  kA<<<512,  256, 0, stream>>>(in_r, in_i, ws_r, ws_i, vp, hb, out);
  kB<<<1024, 256, 0, stream>>>(ws_r, ws_i, vp, hw, out);
}

// Round 9
// 137.154 us; speedup vs baseline: 1.0408x; 1.0408x over previous
//
#include <hip/hip_runtime.h>

// QuantumRegressionModel: 16-qubit statevector, 3 layers x (16 rotations + CNOT chain),
// PauliZ features + linear head. Batch 64, DIM 65536, fp32.
//
// v10 = v8 (PROVEN structure+formulas, 142.7us) with ONLY the lane-exchange layer swapped:
//  * mask32 -> v_permlane32_swap, CORRECTED selection (ISA: swap dst.row1<->src.row0, so
//    with (v,v) inputs r.x={v.lo,v.lo}, r.y={v.hi,v.hi} -> partner = lo ? r.y : r.x).
//    v9 had this inverted (= identity), which corrupted every mask-32 gate.
//  * masks 1,2,3 -> DPP quad_perm (VALU). All other masks stay __shfl_xor (DS).
//  * Arithmetic is bit-identical to v8; only which pipe moves the data changes.
//  Rationale (R7 counters): kB is DS-pipe-bound (occupancy-insensitive, VALUBusy 34%);
//  moving 9/21 kB + 3/5 kA shuffle gates to VALU cuts float-DS 672->384 / 320->128.
// Wire q <-> bit (15-q). State = separate re/im fp32 planes.

typedef float f2 __attribute__((ext_vector_type(2)));
typedef unsigned int u2 __attribute__((ext_vector_type(2)));

struct G8 { float r00,i00,r01,i01,r10,i10,r11,i11; };

__device__ __forceinline__ f2 mkf2(float a, float b) { f2 r; r.x = a; r.y = b; return r; }
__device__ __forceinline__ f2 swp(f2 v) { f2 r; r.x = v.y; r.y = v.x; return r; }
__device__ __forceinline__ f2 sn(f2 v) { f2 r; r.x = -v.y; r.y = v.x; return r; }

// ---- lane-exchange primitives ----
// xor-32 via v_permlane32_swap_b32 (swap dst.row1 <-> src.row0). With (v,v):
// r.x = {v.row0, v.row0}, r.y = {v.row1, v.row1}. Partner: lane<32 -> r.y, lane>=32 -> r.x.
__device__ __forceinline__ float px32s(float v, bool lo) {
  u2 r = __builtin_amdgcn_permlane32_swap(__float_as_uint(v), __float_as_uint(v), false, false);
  return __uint_as_float(lo ? r.y : r.x);
}
__device__ __forceinline__ f2 px32(f2 v, bool lo) { return mkf2(px32s(v.x,lo), px32s(v.y,lo)); }
template<int CTRL>
__device__ __forceinline__ float dpps(float v) {   // quad_perm DPP (lane^1/^2/^3)
  return __int_as_float(__builtin_amdgcn_mov_dpp(__float_as_int(v), CTRL, 0xF, 0xF, false));
}
// dispatcher: compile-time mask after unrolling -> branches fold.
__device__ __forceinline__ f2 ex2(f2 v, int mask, bool lo) {
  if (mask == 32) return px32(v, lo);
  if (mask == 1)  return mkf2(dpps<0xB1>(v.x), dpps<0xB1>(v.y));   // [1,0,3,2]
  if (mask == 2)  return mkf2(dpps<0x4E>(v.x), dpps<0x4E>(v.y));   // [2,3,0,1]
  if (mask == 3)  return mkf2(dpps<0x1B>(v.x), dpps<0x1B>(v.y));   // [3,2,1,0]
  return mkf2(__shfl_xor(v.x, mask), __shfl_xor(v.y, mask));
}

__device__ __forceinline__ G8 loadG(const float* p) {
  G8 g;
  g.r00=p[0]; g.i00=p[1]; g.r01=p[2]; g.i01=p[3];
  g.r10=p[4]; g.i10=p[5]; g.r11=p[6]; g.i11=p[7];
  return g;
}

// ---- kA packing: x = (re, im) in one f2. ----
struct CP { f2 dr, di, br, bi; };
__device__ __forceinline__ CP mkCP(const G8& g, int w) {
  CP c;
  const float a = w ? g.r11 : g.r00, b = w ? g.i11 : g.i00;
  const float p = w ? g.r10 : g.r01, q = w ? g.i10 : g.i01;
  c.dr = mkf2(a,a); c.di = mkf2(b,b); c.br = mkf2(p,p); c.bi = mkf2(q,q);
  return c;
}
__device__ __forceinline__ void supdP(const CP& c, f2& x, f2 p) {
  x = __builtin_elementwise_fma(c.dr, x,
       __builtin_elementwise_fma(c.di, sn(x),
        __builtin_elementwise_fma(c.br, p, c.bi * sn(p))));
}

// ---- kB packing: xr/xi hold (r11=0, r11=1) halves; coeffs may differ per half. ----
struct C2 { f2 dr, di, br, bi; };
__device__ __forceinline__ C2 mkC2(const G8& g, int wlo, int whi) {
  C2 c;
  c.dr = mkf2(wlo ? g.r11 : g.r00, whi ? g.r11 : g.r00);
  c.di = mkf2(wlo ? g.i11 : g.i00, whi ? g.i11 : g.i00);
  c.br = mkf2(wlo ? g.r10 : g.r01, whi ? g.r10 : g.r01);
  c.bi = mkf2(wlo ? g.i10 : g.i01, whi ? g.i10 : g.i01);
  return c;
}
__device__ __forceinline__ void supd2(const C2& c, f2& xr, f2& xi, f2 pr, f2 pi) {
  f2 nr = __builtin_elementwise_fma(c.dr, xr,
           __builtin_elementwise_fma(c.di, -xi,
            __builtin_elementwise_fma(c.br, pr, c.bi * (-pi))));
  f2 ni = __builtin_elementwise_fma(c.dr, xi,
           __builtin_elementwise_fma(c.di, xr,
            __builtin_elementwise_fma(c.br, pi, c.bi * pr)));
  xr = nr; xi = ni;
}

__device__ __forceinline__ void buildU(const float* __restrict__ vp, float* U) {
  const int i = threadIdx.x;
  if (i < 48) {
    const float tx = vp[i*6+0], ty = vp[i*6+1], tz = vp[i*6+2];
    float sx, cx, sy, cy, sz, cz;
    sincosf(0.5f*tx, &sx, &cx);
    sincosf(0.5f*ty, &sy, &cy);
    sincosf(0.5f*tz, &sz, &cz);
    const float m00r = cy*cx,  m00i = sy*sx;
    const float m01r = -sy*cx, m01i = -cy*sx;
    const float m10r = sy*cx,  m10i = -cy*sx;
    const float m11r = cy*cx,  m11i = -sy*sx;
    float* o = U + i*8;
    o[0] = cz*m00r + sz*m00i;  o[1] = cz*m00i - sz*m00r;
    o[2] = cz*m01r + sz*m01i;  o[3] = cz*m01i - sz*m01r;
    o[4] = cz*m10r - sz*m10i;  o[5] = cz*m10i + sz*m10r;
    o[6] = cz*m11r - sz*m11i;  o[7] = cz*m11i + sz*m11r;
  }
}

#define GU(l, w) loadG(Ush + ((l)*16 + (w))*8)

// ---------------- Pass A: bits {15..9}, 17 gates, (re,im)-packed -------------
// j = k<<11 | l5<<10 | l4<<9 | c<<6 | wv<<4 | (l&15). Grid: 64 batch x 8 c.
__global__ void __launch_bounds__(256, 2)
kA(const float* __restrict__ sr, const float* __restrict__ si,
   float* __restrict__ dr, float* __restrict__ di,
   const float* __restrict__ vp, const float* __restrict__ hb, float* __restrict__ out) {
  __shared__ float Ush[384];
  buildU(vp, Ush);
  const int t = threadIdx.x;
  const int l = t & 63, wv = t >> 6;
  const int l5 = (l >> 5) & 1, l4 = (l >> 4) & 1;
  const bool lo32 = (l & 32) == 0;
  const int b = blockIdx.x >> 3, c = blockIdx.x & 7;
  if (blockIdx.x == 0 && t < 64) out[t] = hb[0];     // head bias init
  __syncthreads();

  const size_t bb = (size_t)b << 16;
  const int tb = (l5 << 10) | (l4 << 9) | (c << 6) | (wv << 4) | (l & 15);
  f2 x[32];
  #pragma unroll
  for (int k = 0; k < 32; ++k) {
    const size_t a = bb + (k << 11) + tb;
    x[k] = mkf2(sr[a], si[a]);
  }

#define RPA(CA, CB, A, B) { f2 tt = x[A]; supdP(CA, x[A], x[B]); supdP(CB, x[B], tt); }

  // U0 wires 0..4 on k-bits 4..0
  #pragma unroll
  for (int g = 0; g < 5; ++g) {
    const int kb = 4 - g;
    const G8 U = GU(0, g);
    const CP c0 = mkCP(U, 0), c1 = mkCP(U, 1);
    #pragma unroll
    for (int p = 0; p < 16; ++p) {
      const int i0 = ((p >> kb) << (kb + 1)) | (p & ((1 << kb) - 1));
      RPA(c0, c1, i0, i0 | (1 << kb));
    }
  }
  // U0 wire5 (bit10, mask32 -> permlane)
  { const G8 U = GU(0,5); const CP cc = mkCP(U, l5);
    #pragma unroll
    for (int a = 0; a < 32; ++a) supdP(cc, x[a], ex2(x[a], 32, lo32)); }
  // U0 wire6 (bit9, mask16)
  { const G8 U = GU(0,6); const CP cc = mkCP(U, l4);
    #pragma unroll
    for (int a = 0; a < 32; ++a) supdP(cc, x[a], ex2(x[a], 16, lo32)); }
  // Ũ1 b=15: ^24, rep k4=0, flip 0
  { const G8 U = GU(1,0); const CP c0 = mkCP(U,0), c1 = mkCP(U,1);
    #pragma unroll
    for (int k = 0; k < 32; ++k) if (!((k>>4)&1)) RPA(c0, c1, k, k^24); }
  // Ũ1 b=14: ^12, rep k3=0, flip k4
  { const G8 U = GU(1,1); const CP c0 = mkCP(U,0), c1 = mkCP(U,1);
    #pragma unroll
    for (int k = 0; k < 32; ++k) if (!((k>>3)&1)) {
      const int f = (k>>4)&1;
      RPA(f?c1:c0, f?c0:c1, k, k^12);
    } }
  // Ũ1 b=13: ^6, rep k2=0, flip k4^k3
  { const G8 U = GU(1,2); const CP c0 = mkCP(U,0), c1 = mkCP(U,1);
    #pragma unroll
    for (int k = 0; k < 32; ++k) if (!((k>>2)&1)) {
      const int f = ((k>>4)^(k>>3))&1;
      RPA(f?c1:c0, f?c0:c1, k, k^6);
    } }
  // Ũ1 b=12: ^3, rep k1=0, flip k4^k3^k2
  { const G8 U = GU(1,3); const CP c0 = mkCP(U,0), c1 = mkCP(U,1);
    #pragma unroll
    for (int k = 0; k < 32; ++k) if (!((k>>1)&1)) {
      const int f = ((k>>4)^(k>>3)^(k>>2))&1;
      RPA(f?c1:c0, f?c0:c1, k, k^3);
    } }
  // Ũ1 b=11: dir k0 x mask32; per-amp w = popc(k)
  { const G8 U = GU(1,4); const CP c0 = mkCP(U,0), c1 = mkCP(U,1);
    #pragma unroll
    for (int m = 0; m < 16; ++m) {
      const int k0 = 2*m, k1 = 2*m+1;
      f2 p0 = ex2(x[k1], 32, lo32), p1 = ex2(x[k0], 32, lo32);
      const int w0 = __builtin_popcount(k0)&1;
      supdP(w0?c1:c0, x[k0], p0);
      supdP(w0?c0:c1, x[k1], p1);
    } }
  // Ũ1 b=10: mask48; w = popc(k)^l5
  { const G8 U = GU(1,5); const CP cA = mkCP(U, l5), cB = mkCP(U, l5^1);
    #pragma unroll
    for (int k = 0; k < 32; ++k) {
      f2 p = ex2(x[k], 48, lo32);
      supdP((__builtin_popcount(k)&1)?cB:cA, x[k], p);
    } }
  // Ũ2 b'=15: ^20, rep k4=0, flip 0
  { const G8 U = GU(2,0); const CP c0 = mkCP(U,0), c1 = mkCP(U,1);
    #pragma unroll
    for (int k = 0; k < 32; ++k) if (!((k>>4)&1)) RPA(c0, c1, k, k^20); }
  // Ũ2 b'=14: ^10, rep k3=0, flip 0
  { const G8 U = GU(2,1); const CP c0 = mkCP(U,0), c1 = mkCP(U,1);
    #pragma unroll
    for (int k = 0; k < 32; ++k) if (!((k>>3)&1)) RPA(c0, c1, k, k^10); }
  // Ũ2 b'=13: ^5, rep k2=0, flip k4
  { const G8 U = GU(2,2); const CP c0 = mkCP(U,0), c1 = mkCP(U,1);
    #pragma unroll
    for (int k = 0; k < 32; ++k) if (!((k>>2)&1)) {
      const int f = (k>>4)&1;
      RPA(f?c1:c0, f?c0:c1, k, k^5);
    } }
  // Ũ2 b'=12: dir k1 x mask32; rep k1=0; w0 = k3
  { const G8 U = GU(2,3); const CP c0 = mkCP(U,0), c1 = mkCP(U,1);
    #pragma unroll
    for (int k = 0; k < 32; ++k) if (!((k>>1)&1)) {
      f2 p0 = ex2(x[k^2], 32, lo32), p1 = ex2(x[k], 32, lo32);
      const int f = (k>>3)&1;
      supdP(f?c1:c0, x[k], p0);
      supdP(f?c0:c1, x[k^2], p1);
    } }

  #pragma unroll
  for (int k = 0; k < 32; ++k) {
    const size_t a = bb + (k << 11) + tb;
    dr[a] = x[k].x; di[a] = x[k].y;
  }
#undef RPA
}

// ---------------- Pass B: bits {11..0}, 31 gates, bit11-packed ---------------
// Layout A (stages 1,3): slots s = kk*4+e, kk = bit10, e = bits{1,0}; lanes bits{7..2};
//   waves bits{9,8}; halves r11. Grid: 64 batch x h4 = bits{15..12} -> 1024 blocks.
// Layout B (stage 2, via swizzled LDS retile {9,8}<->{1,0}): slots s3 = bits{10,9,8}.
// LDS: 2048 f2 x 2 planes = 32 KB -> 4 blocks/CU.
__device__ __forceinline__ int SA2(int i) { return i ^ (((i >> 5) & 7) << 1); }

__global__ void __launch_bounds__(256, 4)
kB(const float* __restrict__ sr, const float* __restrict__ si,
   const float* __restrict__ vp, const float* __restrict__ hw, float* __restrict__ out) {
  __shared__ float lds[8192];
  __shared__ float Ush[384];
  __shared__ float red[4];
  buildU(vp, Ush);
  const int t = threadIdx.x;
  const int l = t & 63, wv = t >> 6;
  const bool lo32 = (l & 32) == 0;
  const int b = blockIdx.x >> 4, h4 = blockIdx.x & 15;
  __syncthreads();

  const int ph4 = __builtin_popcount(h4) & 1;       // parity bits {15..12}
  const int pA4 = ((h4 >> 1) ^ (h4 >> 3)) & 1;      // bit13 ^ bit15
  const int pB4 = (h4 ^ (h4 >> 2)) & 1;             // bit12 ^ bit14
  const size_t base0 = ((size_t)b << 16) | (h4 << 12) | (wv << 8) | (l << 2);

  f2 xr2[8], xi2[8];                                 // s = kk*4 + e; halves = r11
  #pragma unroll
  for (int kk = 0; kk < 2; ++kk) {
    const float4 r0 = *(const float4*)(sr + base0 + (kk << 10));
    const float4 r1 = *(const float4*)(sr + base0 + (kk << 10) + 2048);
    const float4 i0 = *(const float4*)(si + base0 + (kk << 10));
    const float4 i1 = *(const float4*)(si + base0 + (kk << 10) + 2048);
    xr2[kk*4+0] = mkf2(r0.x, r1.x); xr2[kk*4+1] = mkf2(r0.y, r1.y);
    xr2[kk*4+2] = mkf2(r0.z, r1.z); xr2[kk*4+3] = mkf2(r0.w, r1.w);
    xi2[kk*4+0] = mkf2(i0.x, i1.x); xi2[kk*4+1] = mkf2(i0.y, i1.y);
    xi2[kk*4+2] = mkf2(i0.z, i1.z); xi2[kk*4+3] = mkf2(i0.w, i1.w);
  }

#define RP2(CA, CB, A, B) { f2 tr = xr2[A], ti = xi2[A]; \
    supd2(CA, xr2[A], xi2[A], xr2[B], xi2[B]); \
    supd2(CB, xr2[B], xi2[B], tr, ti); }

  // ======== Stage 1 (layout A): U0 bits 7..0 ========
  #pragma unroll
  for (int g = 0; g < 6; ++g) {                      // wires 8..13 = lane masks 32..1
    const int mask = 32 >> g;
    const G8 U = GU(0, 8 + g);
    const int hi = (l >> (5 - g)) & 1;
    const C2 cc = mkC2(U, hi, hi);
    #pragma unroll
    for (int s = 0; s < 8; ++s) {
      f2 pr = ex2(xr2[s], mask, lo32), pi = ex2(xi2[s], mask, lo32);
      supd2(cc, xr2[s], xi2[s], pr, pi);
    }
  }
  { const G8 U = GU(0,14);                           // wire 14 = bit1 = e1
    const C2 c0 = mkC2(U,0,0), c1 = mkC2(U,1,1);
    #pragma unroll
    for (int kk = 0; kk < 2; ++kk)
      #pragma unroll
      for (int e0 = 0; e0 < 2; ++e0) RP2(c0, c1, kk*4+e0, kk*4+e0+2); }
  { const G8 U = GU(0,15);                           // wire 15 = bit0 = e0
    const C2 c0 = mkC2(U,0,0), c1 = mkC2(U,1,1);
    #pragma unroll
    for (int kk = 0; kk < 2; ++kk) {
      RP2(c0, c1, kk*4+0, kk*4+1);
      RP2(c0, c1, kk*4+2, kk*4+3);
    } }

  // ---- retile A -> B (swap bits {9,8} <-> {1,0}), b64 swizzled ----
  #pragma unroll
  for (int kk = 0; kk < 2; ++kk)
    #pragma unroll
    for (int e = 0; e < 4; ++e) {
      const int fi = ((kk << 10) | (wv << 8) | (l << 2) | e) << 1;
      *(f2*)&lds[SA2(fi)] = xr2[kk*4+e];
      *(f2*)&lds[4096 + SA2(fi)] = xi2[kk*4+e];
    }
  __syncthreads();
  #pragma unroll
  for (int s3 = 0; s3 < 8; ++s3) {
    const int fi = ((s3 << 8) | (l << 2) | wv) << 1;
    xr2[s3] = *(f2*)&lds[SA2(fi)];
    xi2[s3] = *(f2*)&lds[4096 + SA2(fi)];
  }

  // ======== Stage 2 (layout B: s3 bits {10,9,8}) ========
  const int l5=(l>>5)&1, l4=(l>>4)&1, l3=(l>>3)&1, l2=(l>>2)&1, l1=(l>>1)&1, l0=l&1;
  { const G8 U = GU(0,7);                            // U0 wire 7 = bit8 = s3 bit0
    const C2 c0 = mkC2(U,0,0), c1 = mkC2(U,1,1);
    #pragma unroll
    for (int s3 = 0; s3 < 8; s3 += 2) RP2(c0, c1, s3, s3^1); }
  // Ũ1 b=9 (w6): pairs s3^3; rep b9=0; flip = ph4 ^ r11 ^ b10
  { const G8 U = GU(1,6);
    const C2 cA = mkC2(U, ph4, ph4^1), cB = mkC2(U, ph4^1, ph4);
    #pragma unroll
    for (int s3 = 0; s3 < 8; ++s3) if (!((s3>>1)&1)) {
      const int f = (s3>>2)&1;
      RP2(f?cB:cA, f?cA:cB, s3, s3^3);
    } }
  // Ũ1 b=8 (w7): dir s3bit0 x mask32; w = ph4^r11^b10^b9^b8
  { const G8 U = GU(1,7);
    const C2 cA = mkC2(U, ph4, ph4^1), cB = mkC2(U, ph4^1, ph4);
    #pragma unroll
    for (int s3 = 0; s3 < 8; s3 += 2) {
      f2 p0r = ex2(xr2[s3^1], 32, lo32), p0i = ex2(xi2[s3^1], 32, lo32);
      f2 p1r = ex2(xr2[s3],   32, lo32), p1i = ex2(xi2[s3],   32, lo32);
      const int f = ((s3>>2)^(s3>>1))&1;
      supd2(f?cB:cA, xr2[s3], xi2[s3], p0r, p0i);
      supd2(f?cA:cB, xr2[s3^1], xi2[s3^1], p1r, p1i);
    } }
  // Ũ1 b=7..3 (w8..12): lane masks 48,24,12,6,3; w = lp ^ ph4 ^ r11 ^ popc(s3)
  #pragma unroll
  for (int g = 0; g < 5; ++g) {
    const int mask = 48 >> g;
    const G8 U = GU(1, 8 + g);
    const int lp = (g==0)? l5 : (g==1)? (l4^l5) : (g==2)? (l3^l4^l5)
                 : (g==3)? (l2^l3^l4^l5) : (l1^l2^l3^l4^l5);
    const C2 cA = mkC2(U, (lp^ph4)&1, (lp^ph4^1)&1);
    const C2 cB = mkC2(U, (lp^ph4^1)&1, (lp^ph4)&1);
    #pragma unroll
    for (int s3 = 0; s3 < 8; ++s3) {
      f2 pr = ex2(xr2[s3], mask, lo32), pi = ex2(xi2[s3], mask, lo32);
      supd2((__builtin_popcount(s3)&1)?cB:cA, xr2[s3], xi2[s3], pr, pi);
    }
  }
  // Ũ2 b'=11 (w4): dir {11,9} crosses pack: partner = swp(s3^2); w = r11^pA4
  { const G8 U = GU(2,4);
    const C2 cc = mkC2(U, pA4, pA4^1);
    #pragma unroll
    for (int s3 = 0; s3 < 8; ++s3) if (!((s3>>1)&1)) {
      f2 tr = xr2[s3], ti = xi2[s3];
      supd2(cc, xr2[s3], xi2[s3], swp(xr2[s3^2]), swp(xi2[s3^2]));
      supd2(cc, xr2[s3^2], xi2[s3^2], swp(tr), swp(ti));
    } }
  // Ũ2 b'=10 (w5): pairs s3^5; rep b10=0; flip = pB4
  { const G8 U = GU(2,5);
    const C2 cA = mkC2(U, pB4, pB4), cB = mkC2(U, pB4^1, pB4^1);
    #pragma unroll
    for (int s3 = 0; s3 < 4; ++s3) RP2(cA, cB, s3, s3^5); }
  // Ũ2 b'=9 (w6): dir s3bit1 x mask32; w(b9=0) = r11^pA4
  { const G8 U = GU(2,6);
    const C2 cA = mkC2(U, pA4, pA4^1), cB = mkC2(U, pA4^1, pA4);
    #pragma unroll
    for (int s3 = 0; s3 < 8; ++s3) if (!((s3>>1)&1)) {
      f2 p0r = ex2(xr2[s3^2], 32, lo32), p0i = ex2(xi2[s3^2], 32, lo32);
      f2 p1r = ex2(xr2[s3],   32, lo32), p1i = ex2(xi2[s3],   32, lo32);
      supd2(cA, xr2[s3], xi2[s3], p0r, p0i);
      supd2(cB, xr2[s3^2], xi2[s3^2], p1r, p1i);
    } }
  // Ũ2 b'=8 (w7): dir s3bit0 x mask16; w(b8=0) = b10^pB4
  { const G8 U = GU(2,7);
    const C2 cA = mkC2(U, pB4, pB4), cB = mkC2(U, pB4^1, pB4^1);
    #pragma unroll
    for (int s3 = 0; s3 < 8; s3 += 2) {
      f2 p0r = ex2(xr2[s3^1], 16, lo32), p0i = ex2(xi2[s3^1], 16, lo32);
      f2 p1r = ex2(xr2[s3],   16, lo32), p1i = ex2(xi2[s3],   16, lo32);
      const int f = (s3>>2)&1;
      supd2(f?cB:cA, xr2[s3], xi2[s3], p0r, p0i);
      supd2(f?cA:cB, xr2[s3^1], xi2[s3^1], p1r, p1i);
    } }
  // Ũ2 b'=7,6,5 (w8,9,10): lane masks 40,20,10
  #pragma unroll
  for (int g = 0; g < 3; ++g) {
    const int mask = (g == 0) ? 40 : (g == 1) ? 20 : 10;
    const G8 U = GU(2, 8 + g);
    int mpar, blo, bhi;
    if      (g == 0) { mpar = 2; blo = (l5^pA4)&1;      bhi = blo^1; }  // w = l5^b9^r11^pA4
    else if (g == 1) { mpar = 5; blo = (l4^pB4)&1;      bhi = blo;   }  // w = l4^b8^b10^pB4
    else             { mpar = 2; blo = (l3^l5^pA4)&1;   bhi = blo^1; }  // w = l3^l5^b9^r11^pA4
    const C2 cA = mkC2(U, blo, bhi), cB = mkC2(U, blo^1, bhi^1);
    #pragma unroll
    for (int s3 = 0; s3 < 8; ++s3) {
      f2 pr = ex2(xr2[s3], mask, lo32), pi = ex2(xi2[s3], mask, lo32);
      supd2((__builtin_popcount(s3 & mpar)&1)?cB:cA, xr2[s3], xi2[s3], pr, pi);
    }
  }

  // ---- retile B -> A ----
  __syncthreads();
  #pragma unroll
  for (int s3 = 0; s3 < 8; ++s3) {
    const int fi = ((s3 << 8) | (l << 2) | wv) << 1;
    *(f2*)&lds[SA2(fi)] = xr2[s3];
    *(f2*)&lds[4096 + SA2(fi)] = xi2[s3];
  }
  __syncthreads();
  #pragma unroll
  for (int kk = 0; kk < 2; ++kk)
    #pragma unroll
    for (int e = 0; e < 4; ++e) {
      const int fi = ((kk << 10) | (wv << 8) | (l << 2) | e) << 1;
      xr2[kk*4+e] = *(f2*)&lds[SA2(fi)];
      xi2[kk*4+e] = *(f2*)&lds[4096 + SA2(fi)];
    }

  // ======== Stage 3 (layout A) ========
  const int wv1 = (wv >> 1) & 1, wv0 = wv & 1;
  const int RPlo  = (__builtin_popcount(l) ^ __builtin_popcount(wv) ^ ph4) & 1;
  const int oddTl = (l1 ^ l3 ^ l5 ^ wv1 ^ pA4) & 1;
  const int evB   = (l0 ^ l2 ^ l4 ^ wv0 ^ pB4) & 1;
  // Ũ1 b=2 (w13): lane-mask1 x e1; w = RPlo ^ r11 ^ kk
  { const G8 U = GU(1,13);
    const C2 cA = mkC2(U, RPlo, RPlo^1), cB = mkC2(U, RPlo^1, RPlo);
    #pragma unroll
    for (int kk = 0; kk < 2; ++kk) {
      const C2& cc = kk ? cB : cA;
      #pragma unroll
      for (int e0 = 0; e0 < 2; ++e0) {
        const int a = kk*4 + e0, a2 = a + 2;
        f2 par = ex2(xr2[a2], 1, lo32), pai = ex2(xi2[a2], 1, lo32);
        f2 pbr = ex2(xr2[a],  1, lo32), pbi = ex2(xi2[a],  1, lo32);
        supd2(cc, xr2[a],  xi2[a],  par, pai);
        supd2(cc, xr2[a2], xi2[a2], pbr, pbi);
      }
    } }
  // Ũ1 b=1 (w14): pairs (0,3),(1,2); flip = RPlo ^ r11 ^ kk
  { const G8 U = GU(1,14);
    const C2 cA = mkC2(U, RPlo, RPlo^1), cB = mkC2(U, RPlo^1, RPlo);
    #pragma unroll
    for (int kk = 0; kk < 2; ++kk) {
      RP2(kk?cB:cA, kk?cA:cB, kk*4+0, kk*4+3);
      RP2(kk?cB:cA, kk?cA:cB, kk*4+1, kk*4+2);
    } }
  // Ũ1 b=0 (w15): pairs s^1; flip = RPlo ^ r11 ^ kk ^ e1
  { const G8 U = GU(1,15);
    const C2 cA = mkC2(U, RPlo, RPlo^1), cB = mkC2(U, RPlo^1, RPlo);
    #pragma unroll
    for (int kk = 0; kk < 2; ++kk) {
      RP2(kk?cB:cA, kk?cA:cB, kk*4+0, kk*4+1);
      RP2(kk?cA:cB, kk?cB:cA, kk*4+2, kk*4+3);
    } }
  // Ũ2 b'=4 (w11): lane mask 5; parity set {4,6,8,10,12,14} -> w = (l2^l4^wv0^pB4) ^ kk
  { const G8 U = GU(2,11);
    const int b4 = (l2 ^ l4 ^ wv0 ^ pB4) & 1;
    const C2 cA = mkC2(U, b4, b4), cB = mkC2(U, b4^1, b4^1);
    #pragma unroll
    for (int s = 0; s < 8; ++s) {
      f2 pr = ex2(xr2[s], 5, lo32), pi = ex2(xi2[s], 5, lo32);
      supd2((s>>2)?cB:cA, xr2[s], xi2[s], pr, pi);
    } }
  // Ũ2 b'=3 (w12): lane-mask2 x e1; w = oddTl ^ r11 (no kk)
  { const G8 U = GU(2,12);
    const C2 cc = mkC2(U, oddTl, oddTl^1);
    #pragma unroll
    for (int kk = 0; kk < 2; ++kk)
      #pragma unroll
      for (int e0 = 0; e0 < 2; ++e0) {
        const int a = kk*4 + e0, a2 = a + 2;
        f2 par = ex2(xr2[a2], 2, lo32), pai = ex2(xi2[a2], 2, lo32);
        f2 pbr = ex2(xr2[a],  2, lo32), pbi = ex2(xi2[a],  2, lo32);
        supd2(cc, xr2[a],  xi2[a],  par, pai);
        supd2(cc, xr2[a2], xi2[a2], pbr, pbi);
      } }
  // Ũ2 b'=2 (w13): lane-mask1 x e0; w = evB ^ kk
  { const G8 U = GU(2,13);
    const C2 cA = mkC2(U, evB, evB), cB = mkC2(U, evB^1, evB^1);
    #pragma unroll
    for (int kk = 0; kk < 2; ++kk) {
      const C2& cc = kk ? cB : cA;
      #pragma unroll
      for (int e0 = 0; e0 < 4; e0 += 2) {
        const int a = kk*4 + e0, a2 = a + 1;
        f2 par = ex2(xr2[a2], 1, lo32), pai = ex2(xi2[a2], 1, lo32);
        f2 pbr = ex2(xr2[a],  1, lo32), pbi = ex2(xi2[a],  1, lo32);
        supd2(cc, xr2[a],  xi2[a],  par, pai);
        supd2(cc, xr2[a2], xi2[a2], pbr, pbi);
      }
    } }
  // Ũ2 b'=1 (w14): pairs s^2; flip = oddTl ^ r11
  { const G8 U = GU(2,14);
    const C2 cA = mkC2(U, oddTl, oddTl^1), cB = mkC2(U, oddTl^1, oddTl);
    #pragma unroll
    for (int kk = 0; kk < 2; ++kk) {
      RP2(cA, cB, kk*4+0, kk*4+2);
      RP2(cA, cB, kk*4+1, kk*4+3);
    } }
  // Ũ2 b'=0 (w15): pairs s^1; flip = evB ^ kk
  { const G8 U = GU(2,15);
    const C2 cA = mkC2(U, evB, evB), cB = mkC2(U, evB^1, evB^1);
    #pragma unroll
    for (int kk = 0; kk < 2; ++kk) {
      RP2(kk?cB:cA, kk?cA:cB, kk*4+0, kk*4+1);
      RP2(kk?cB:cA, kk?cA:cB, kk*4+2, kk*4+3);
    } }

  // ======== Features (P^3 fold, bit11 per-half) + head ========
  #pragma unroll
  for (int s = 0; s < 8; ++s)
    xr2[s] = xr2[s]*xr2[s] + xi2[s]*xi2[s];          // reuse as |amp|^2
  const int jloc = (h4 << 12) | (wv << 8) | (l << 2);
  float hsum = 0.f;
  #pragma unroll
  for (int q = 0; q < 16; ++q) {
    const int M = (0x3333 << (15 - q)) & 0xFFFF;
    f2 acc = mkf2(0.f, 0.f);
    #pragma unroll
    for (int s = 0; s < 8; ++s) {
      const int amp = ((s >> 2) << 10) | (s & 3);
      if (__builtin_popcount(amp & M) & 1) acc -= xr2[s]; else acc += xr2[s];
    }
    float sv = acc.x + (((M >> 11) & 1) ? -acc.y : acc.y);
    if (__builtin_popcount(jloc & M) & 1) sv = -sv;
    hsum += hw[q] * sv;
  }
  #pragma unroll
  for (int o = 32; o >= 1; o >>= 1) hsum += __shfl_xor(hsum, o);
  if ((t & 63) == 0) red[wv] = hsum;
  __syncthreads();
  if (t == 0) atomicAdd(out + b, red[0] + red[1] + red[2] + red[3]);
#undef RP2
}

extern "C" void kernel_launch(void* const* d_in, const int* in_sizes, int n_in,
                              void* d_out, int out_size, void* d_ws, size_t ws_size,
                              hipStream_t stream) {
  const float* in_r = (const float*)d_in[0];  // (64, 65536) fp32
  const float* in_i = (const float*)d_in[1];
  const float* vp = (const float*)d_in[2];    // (3,16,6)
  const float* hw = (const float*)d_in[3];    // (1,16)
  const float* hb = (const float*)d_in[4];    // (1,)
  float* out = (float*)d_out;                 // (64,) fp32

  float* ws_r = (float*)d_ws;                 // 4,194,304 floats
  float* ws_i = ws_r + 4194304ull;

  kA<<<512,  256, 0, stream>>>(in_r, in_i, ws_r, ws_i, vp, hb, out);
  kB<<<1024, 256, 0, stream>>>(ws_r, ws_i, vp, hw, out);
}